// Round 14
// baseline (153.364 us; speedup 1.0000x reference)
//
#include <hip/hip_runtime.h>
#include <hip/hip_bf16.h>

// ---------------------------------------------------------------------------
// BidirectionalGINConv: out = relu(0.5*(gin(ei) + gin(rei)))
// Restructured (linearity of segsum; shared w2):
//   z = x@w1^T                 (bf16 MFMA GEMM, fused into partition launch)
//   adjacency: partition into 256-node bucket slabs -> in-LDS counting sort CSR
//   agg_i = segsum(z[src_i])   (1-node-per-wave gather, 16/8/4 batches — r9)
//   s -> LDS tile, out = relu(s@w2^T + b2) MFMA in the SAME kernel (r14)
// NOTES:
//   r7:  LDS f32 atomicAdd = CAS retry loop on gfx950 -> never on critical path.
//   r8:  prep_k OOB clobbered wbf2 -> 32 conversion blocks + 1 cursor block.
//   r10: XCD-affine column-quartering regressed: no L2 affinity, 4x less MLP.
//   r11: 32-wide batch regressed: compiler serializes >16-deep batches.
//   r12: 4-waves-per-node regressed gather (overhead-bound at 50K tiny blocks),
//        but partition||gemm1 fusion saved ~17us.
//   r13: r9 gather + r12 fusion = 124us. Gather floor: 8-XCD z replication
//        (109MB compulsory) at ~2.75TB/s LLC service => ~40-55us. fp8 z
//        rejected on error budget (~0.05-0.08 vs 0.0887 threshold).
//   r14: fuse gather + gemm2: block=64 nodes, wave gathers its own 16 rows
//        into LDS [64][65] (pad -> conflict-free A-frag reads, no barrier
//        needed), then MFMA + f32 epilogue. Kills gemm2 dispatch + s
//        round-trip. MFMA loop reordered (acc 1x f32x4 live) to stay <=64 VGPR.
// ---------------------------------------------------------------------------

#define C_BKT    196     // coarse buckets: b = dst>>8 (256 nodes each)
#define SLAB_CAP 4608    // per-bucket slab capacity; mean 4096 -> +8 sigma
#define CHUNK    4096    // edges per partition block

typedef __attribute__((ext_vector_type(8))) short short8;
typedef __attribute__((ext_vector_type(4))) float f32x4;

__device__ inline unsigned packbf2(float f0, float f1) {   // RNE bf16 pair
    unsigned u0 = __float_as_uint(f0), u1 = __float_as_uint(f1);
    u0 = (u0 + 0x7fffu + ((u0 >> 16) & 1u)) >> 16;
    u1 = (u1 + 0x7fffu + ((u1 >> 16) & 1u)) >> 16;
    return u0 | (u1 << 16);
}

#define BFLO(p) __uint_as_float((p) << 16)
#define BFHI(p) __uint_as_float((p) & 0xffff0000u)

// prep: convert w1,w2 (8192 float2 pairs each) to bf16-packed uints + cursors.
__global__ void prep_k(const float* __restrict__ w1, const float* __restrict__ w2,
                       unsigned* __restrict__ wbf1, unsigned* __restrict__ wbf2,
                       int* __restrict__ gcur1, int* __restrict__ gcur2) {
    int b = blockIdx.x, t = threadIdx.x;
    if (b == 32) {
        if (t < C_BKT) { gcur1[t] = t * SLAB_CAP; gcur2[t] = t * SLAB_CAP; }
        return;
    }
    int p = b * 256 + t;                 // pair index 0..8191
    const float2 v1 = ((const float2*)w1)[p];
    const float2 v2 = ((const float2*)w2)[p];
    wbf1[p] = packbf2(v1.x, v1.y);
    wbf2[p] = packbf2(v2.x, v2.y);
}

// ---------------- fused partition || gemm1 ----------------
__device__ void partition_body(char* smem, int bx,
        const int* __restrict__ src1, const int* __restrict__ dst1,
        const int* __restrict__ src2, const int* __restrict__ dst2,
        unsigned* __restrict__ slab1, unsigned* __restrict__ slab2,
        int* __restrict__ gcur1, int* __restrict__ gcur2, int E, int NB) {
    unsigned* sorted = (unsigned*)smem;              // 16 KB
    unsigned* gpos   = sorted + CHUNK;               // 16 KB
    int* hist = (int*)(gpos + CHUNK);                // 1 KB
    int* loff = hist + 256;
    int* goff = loff + 256;
    int* cur  = goff + 256;

    int t = threadIdx.x;
    int dir = (bx >= NB) ? 1 : 0;
    int cb = dir ? (bx - NB) : bx;
    const int* srcp = dir ? src2 : src1;
    const int* dstp = dir ? dst2 : dst1;
    unsigned* slab = dir ? slab2 : slab1;
    int* gcur = dir ? gcur2 : gcur1;

    hist[t] = 0;
    __syncthreads();

    unsigned vv[16]; int bb[16];
    int base = cb * CHUNK;
    #pragma unroll
    for (int k = 0; k < 16; ++k) {
        int i = base + k * 256 + t;
        if (i < E) {
            int s = srcp[i], d = dstp[i];
            bb[k] = d >> 8;
            vv[k] = ((unsigned)(d & 255) << 16) | (unsigned)s;
            atomicAdd(&hist[bb[k]], 1);
        } else bb[k] = -1;
    }
    __syncthreads();

    int c = hist[t];
    if (t < C_BKT && c > 0) goff[t] = atomicAdd(&gcur[t], c);
    for (int d = 1; d < 256; d <<= 1) {
        int v = (t >= d) ? hist[t - d] : 0;
        __syncthreads();
        hist[t] += v;
        __syncthreads();
    }
    loff[t] = hist[t] - c;
    cur[t] = 0;
    __syncthreads();
    int nv = hist[255];

    #pragma unroll
    for (int k = 0; k < 16; ++k) {
        if (bb[k] >= 0) {
            int b = bb[k];
            int r = atomicAdd(&cur[b], 1);
            int p = loff[b] + r;
            sorted[p] = vv[k];
            int gp = goff[b] + r;
            gpos[p] = (gp < (b + 1) * SLAB_CAP) ? (unsigned)gp : 0xFFFFFFFFu;
        }
    }
    __syncthreads();

    for (int j = t; j < nv; j += 256) {
        unsigned gp = gpos[j];
        if (gp != 0xFFFFFFFFu) slab[gp] = sorted[j];
    }
}

// MFMA 16x16x32 bf16. Block = 4 waves; wave w -> rows [bx*64 + w*16, +16).
// A/B share the same per-lane k-mapping (k-permutation invariant).
// C/D: col=lane&15, row=(lane>>4)*4+reg  [m89-verified].
__device__ void gemm1_body(char* smem, int bx,
        const float* __restrict__ A, const unsigned* __restrict__ wbf,
        unsigned* __restrict__ zb, int M) {
    float* cst = (float*)smem;                       // 64*129*4 = 33 KB
    int t = threadIdx.x;
    int lane = t & 63, wv = t >> 6;
    int l16 = lane & 15, kg = lane >> 4;
    int rowBase = bx * 64 + wv * 16;
    int ar = rowBase + l16; if (ar >= M) ar = M - 1;

    f32x4 acc[8];
    #pragma unroll
    for (int ct = 0; ct < 8; ++ct) acc[ct] = (f32x4){0.f, 0.f, 0.f, 0.f};

    const float4* arow = (const float4*)(A + (size_t)ar * 128);
    #pragma unroll
    for (int kt = 0; kt < 4; ++kt) {
        float4 v0 = arow[kt * 8 + kg * 2];
        float4 v1 = arow[kt * 8 + kg * 2 + 1];
        uint4 au = make_uint4(packbf2(v0.x, v0.y), packbf2(v0.z, v0.w),
                              packbf2(v1.x, v1.y), packbf2(v1.z, v1.w));
        short8 a = *(short8*)&au;
        #pragma unroll
        for (int ct = 0; ct < 8; ++ct) {
            uint4 bu = *(const uint4*)(wbf + (size_t)(ct * 16 + l16) * 64 + kt * 16 + kg * 4);
            short8 b = *(short8*)&bu;
            acc[ct] = __builtin_amdgcn_mfma_f32_16x16x32_bf16(a, b, acc[ct], 0, 0, 0);
        }
    }

    #pragma unroll
    for (int ct = 0; ct < 8; ++ct)
        #pragma unroll
        for (int r = 0; r < 4; ++r)
            cst[(wv * 16 + kg * 4 + r) * 129 + ct * 16 + l16] = acc[ct][r];
    __syncthreads();

    int row = t & 63, q = t >> 6;
    int grow = bx * 64 + row;
    if (grow < M) {
        const float* src = cst + row * 129 + q * 32;
        unsigned pk[16];
        #pragma unroll
        for (int i = 0; i < 16; ++i) pk[i] = packbf2(src[2 * i], src[2 * i + 1]);
        uint4* dst = (uint4*)(zb + (size_t)grow * 64 + q * 16);
        #pragma unroll
        for (int qq = 0; qq < 4; ++qq)
            dst[qq] = make_uint4(pk[4 * qq], pk[4 * qq + 1], pk[4 * qq + 2], pk[4 * qq + 3]);
    }
}

__global__ __launch_bounds__(256) void pg_k(
        const int* __restrict__ src1, const int* __restrict__ dst1,
        const int* __restrict__ src2, const int* __restrict__ dst2,
        unsigned* __restrict__ slab1, unsigned* __restrict__ slab2,
        int* __restrict__ gcur1, int* __restrict__ gcur2, int E, int NB,
        const float* __restrict__ x, const unsigned* __restrict__ wbf1,
        unsigned* __restrict__ zb, int M) {
    __shared__ __align__(16) char smem[36864];
    int bx = blockIdx.x;
    if (bx < 2 * NB)
        partition_body(smem, bx, src1, dst1, src2, dst2,
                       slab1, slab2, gcur1, gcur2, E, NB);
    else
        gemm1_body(smem, bx - 2 * NB, x, wbf1, zb, M);
}

// Phase B: per (bucket, dir): counting-sort slab by node in LDS, emit exact CSR.
__global__ __launch_bounds__(256) void csr_k(
        const unsigned* __restrict__ slab1, const unsigned* __restrict__ slab2,
        const int* __restrict__ gcur1, const int* __restrict__ gcur2,
        unsigned short* __restrict__ list1, unsigned short* __restrict__ list2,
        unsigned* __restrict__ goff1, unsigned* __restrict__ goff2,
        unsigned short* __restrict__ gcnt1, unsigned short* __restrict__ gcnt2,
        int N) {
    __shared__ unsigned short srt[SLAB_CAP];
    __shared__ int cnt[256], loff[256], cur[256];

    int t = threadIdx.x;
    int dir = (blockIdx.x >= C_BKT) ? 1 : 0;
    int b = dir ? (blockIdx.x - C_BKT) : blockIdx.x;
    const unsigned* sl = (dir ? slab2 : slab1) + (size_t)b * SLAB_CAP;
    unsigned short* lst = dir ? list2 : list1;
    unsigned* goffN = dir ? goff2 : goff1;
    unsigned short* gcntN = dir ? gcnt2 : gcnt1;
    int nv = (dir ? gcur2 : gcur1)[b] - b * SLAB_CAP;
    if (nv > SLAB_CAP) nv = SLAB_CAP;

    cnt[t] = 0;
    __syncthreads();
    for (int j = t; j < nv; j += 256) atomicAdd(&cnt[sl[j] >> 16], 1);
    __syncthreads();

    int c = cnt[t];
    for (int d = 1; d < 256; d <<= 1) {
        int v = (t >= d) ? cnt[t - d] : 0;
        __syncthreads();
        cnt[t] += v;
        __syncthreads();
    }
    loff[t] = cnt[t] - c;
    cur[t] = 0;
    int node = b * 256 + t;
    if (node < N) {
        goffN[node] = (unsigned)(b * SLAB_CAP + loff[t]);
        gcntN[node] = (unsigned short)c;
    }
    __syncthreads();

    for (int j = t; j < nv; j += 256) {
        unsigned v = sl[j];
        int n = v >> 16;
        int r = atomicAdd(&cur[n], 1);
        srt[loff[n] + r] = (unsigned short)(v & 0xffffu);
    }
    __syncthreads();
    for (int j = t; j < nv; j += 256)
        lst[(size_t)b * SLAB_CAP + j] = srt[j];
}

// ---------------- fused gather + GEMM2 ----------------
template<int B>
__device__ inline void batchsum(const unsigned short* __restrict__ lst, int o,
                                const unsigned* __restrict__ zb, int lane,
                                float& ax, float& ay) {
    unsigned idx[B], pv[B];
    #pragma unroll
    for (int u = 0; u < B; ++u) idx[u] = lst[o + u];
    #pragma unroll
    for (int u = 0; u < B; ++u) pv[u] = zb[(size_t)idx[u] * 64 + lane];
    float sx = 0.f, sy = 0.f;
    #pragma unroll
    for (int u = 0; u < B; ++u) { sx += BFLO(pv[u]); sy += BFHI(pv[u]); }
    ax += sx; ay += sy;
}

// Block = 64 nodes, 4 waves. Wave w gathers rows [w*16, w*16+16) into the
// LDS s-tile (bf16-packed, [64][65] pad -> conflict-free A-frag reads), then
// MFMAs those SAME rows (no cross-wave dep => no __syncthreads; per-wave LDS
// ops are in-order). MFMA loop keeps ONE f32x4 acc live (<=64 VGPR target).
__global__ __launch_bounds__(256) void gg_k(
        const unsigned* __restrict__ zb,
        const unsigned* __restrict__ goff1, const unsigned short* __restrict__ gcnt1,
        const unsigned short* __restrict__ list1,
        const unsigned* __restrict__ goff2, const unsigned short* __restrict__ gcnt2,
        const unsigned short* __restrict__ list2,
        const float* __restrict__ b1, const unsigned* __restrict__ wbf,
        const float* __restrict__ bias2, float* __restrict__ O, int N) {
    __shared__ unsigned st[64][65];
    int t = threadIdx.x;
    int w = t >> 6, lane = t & 63;
    int rowBase = blockIdx.x * 64;
    float2 bb = ((const float2*)b1)[lane];

    // ---- phase 1: gather 16 nodes (r9 body per node) ----
    for (int i = 0; i < 16; ++i) {
        int r = w * 16 + i;
        int g = __builtin_amdgcn_readfirstlane(rowBase + r);
        unsigned pk = 0;
        if (g < N) {
            float a1x = 0.f, a1y = 0.f, a2x = 0.f, a2y = 0.f;
            {
                int o = (int)goff1[g], c = (int)gcnt1[g], j = 0;
                for (; j + 16 <= c; j += 16) batchsum<16>(list1, o + j, zb, lane, a1x, a1y);
                if (j + 8 <= c) { batchsum<8>(list1, o + j, zb, lane, a1x, a1y); j += 8; }
                if (j + 4 <= c) { batchsum<4>(list1, o + j, zb, lane, a1x, a1y); j += 4; }
                for (; j < c; ++j) {
                    unsigned p = zb[(size_t)list1[o + j] * 64 + lane];
                    a1x += BFLO(p); a1y += BFHI(p);
                }
            }
            {
                int o = (int)goff2[g], c = (int)gcnt2[g], j = 0;
                for (; j + 16 <= c; j += 16) batchsum<16>(list2, o + j, zb, lane, a2x, a2y);
                if (j + 8 <= c) { batchsum<8>(list2, o + j, zb, lane, a2x, a2y); j += 8; }
                if (j + 4 <= c) { batchsum<4>(list2, o + j, zb, lane, a2x, a2y); j += 4; }
                for (; j < c; ++j) {
                    unsigned p = zb[(size_t)list2[o + j] * 64 + lane];
                    a2x += BFLO(p); a2y += BFHI(p);
                }
            }
            unsigned pz = zb[(size_t)g * 64 + lane];
            float bx = BFLO(pz) + bb.x, by = BFHI(pz) + bb.y;
            float ox = 0.5f * (fmaxf(bx + a1x, 0.f) + fmaxf(bx + a2x, 0.f));
            float oy = 0.5f * (fmaxf(by + a1y, 0.f) + fmaxf(by + a2y, 0.f));
            pk = packbf2(ox, oy);
        }
        st[r][lane] = pk;
    }

    // ---- phase 2: MFMA rows [w*16, w*16+16) x wbf2 -> relu(+b2) f32 ----
    int l16 = lane & 15, kg = lane >> 4;
    uint4 a[4];
    #pragma unroll
    for (int kt = 0; kt < 4; ++kt)
        a[kt] = *(const uint4*)&st[w * 16 + l16][kt * 16 + kg * 4];

    #pragma unroll
    for (int ct = 0; ct < 8; ++ct) {
        f32x4 acc = (f32x4){0.f, 0.f, 0.f, 0.f};
        #pragma unroll
        for (int kt = 0; kt < 4; ++kt) {
            uint4 bu = *(const uint4*)(wbf + (size_t)(ct * 16 + l16) * 64 + kt * 16 + kg * 4);
            acc = __builtin_amdgcn_mfma_f32_16x16x32_bf16(
                *(short8*)&a[kt], *(short8*)&bu, acc, 0, 0, 0);
        }
        int col = ct * 16 + l16;
        float bv = bias2[col];
        #pragma unroll
        for (int r = 0; r < 4; ++r) {
            int grow = rowBase + w * 16 + kg * 4 + r;
            if (grow < N)
                O[(size_t)grow * 128 + col] = fmaxf(acc[r] + bv, 0.f);
        }
    }
}

extern "C" void kernel_launch(void* const* d_in, const int* in_sizes, int n_in,
                              void* d_out, int out_size, void* d_ws, size_t ws_size,
                              hipStream_t stream) {
    const float* x   = (const float*)d_in[0];
    const int*   ei  = (const int*)d_in[1];
    const int*   rei = (const int*)d_in[2];
    const float* w1  = (const float*)d_in[3];
    const float* b1  = (const float*)d_in[4];
    const float* w2  = (const float*)d_in[5];
    const float* b2  = (const float*)d_in[6];
    float* out = (float*)d_out;

    const int N = in_sizes[0] / 128;      // 50000
    const int E = in_sizes[1] / 2;        // 800000
    const size_t ND = (size_t)N * 128;
    const size_t SL = (size_t)C_BKT * SLAB_CAP;   // 903168

    // ws layout (~25 MB)
    unsigned* zb    = (unsigned*)d_ws;            // N*64  (bf16 z, 12.8 MB)
    unsigned* wbf1  = zb + ND / 2;                // 8192  (bf16 w1, 32 KB)
    unsigned* wbf2  = wbf1 + 8192;                // 8192
    unsigned* slab1 = wbf2 + 8192;                // SL
    unsigned* slab2 = slab1 + SL;                 // SL
    unsigned* goff1 = slab2 + SL;                 // N
    unsigned* goff2 = goff1 + N;                  // N
    int*      gcur1 = (int*)(goff2 + N);          // C_BKT
    int*      gcur2 = gcur1 + C_BKT;              // C_BKT
    unsigned short* gcnt1 = (unsigned short*)(gcur2 + C_BKT);  // N
    unsigned short* gcnt2 = gcnt1 + N;            // N
    unsigned short* list1 = gcnt2 + N;            // SL
    unsigned short* list2 = list1 + SL;           // SL

    const int* src1 = ei,  *dst1 = ei + E;
    const int* src2 = rei, *dst2 = rei + E;

    // 1. weight bf16 convert (8192 pairs = 32 blocks) + slab cursor init
    prep_k<<<33, 256, 0, stream>>>(w1, w2, wbf1, wbf2, gcur1, gcur2);

    // 2. fused: partition (392 blocks) || gemm1 (782 blocks)
    int NB = (E + CHUNK - 1) / CHUNK;   // 196
    int gB = (N + 63) / 64;             // 782
    pg_k<<<2 * NB + gB, 256, 0, stream>>>(src1, dst1, src2, dst2,
                                          slab1, slab2, gcur1, gcur2, E, NB,
                                          x, wbf1, zb, N);

    // 3. in-LDS counting sort -> exact CSR
    csr_k<<<2 * C_BKT, 256, 0, stream>>>(slab1, slab2, gcur1, gcur2,
                                         list1, list2, goff1, goff2,
                                         gcnt1, gcnt2, N);

    // 4. fused gather + activation + GEMM2 -> out (f32)
    gg_k<<<gB, 256, 0, stream>>>(zb, goff1, gcnt1, list1,
                                 goff2, gcnt2, list2, b1, wbf2, b2, out, N);
}

// Round 15
// 130.271 us; speedup vs baseline: 1.1773x; 1.1773x over previous
//
#include <hip/hip_runtime.h>
#include <hip/hip_bf16.h>

// ---------------------------------------------------------------------------
// BidirectionalGINConv: out = relu(0.5*(gin(ei) + gin(rei)))
// Restructured (linearity of segsum; shared w2):
//   z = x@w1^T                 (bf16 MFMA GEMM, fused into partition launch)
//   adjacency: partition into 256-node bucket slabs -> in-LDS counting sort CSR
//   agg_i = segsum(z[src_i])   (1-node-per-wave gather, 16/8/4 batches — r9)
//   s -> LDS tile, out = relu(s@w2^T + b2) MFMA in the SAME kernel
// NOTES:
//   r7:  LDS f32 atomicAdd = CAS retry loop on gfx950 -> never on critical path.
//   r8:  prep_k OOB clobbered wbf2 -> 32 conversion blocks + 1 cursor block.
//   r10: XCD-affine column-quartering regressed: no L2 affinity, 4x less MLP.
//   r11: 32-wide batch regressed: compiler serializes >16-deep batches.
//   r12: 4-waves-per-node regressed gather; partition||gemm1 fusion saved ~17us.
//   r13: r9 gather + r12 fusion = 124us. Gather floor ~109MB compulsory
//        (8-XCD z replication) @ ~2.75TB/s LLC service => ~40-55us.
//   r14: gather+gemm2 fusion at 256-thr blocks regressed (Occ 29%, BW 1.6TB/s):
//        grid tied to GEMM tiles cut wave pool 16x. Lesson: latency-bound
//        gather needs ~12K+ waves regardless of tiling.
//   r15: same fusion, 1024-thr blocks (16 waves): gather = 4 nodes/wave across
//        16 waves (wave pool restored to ~12.5K), __syncthreads, then waves
//        0-3 do the MFMA tiles. Keeps -12us gemm2 and -25MB s round-trip.
// ---------------------------------------------------------------------------

#define C_BKT    196     // coarse buckets: b = dst>>8 (256 nodes each)
#define SLAB_CAP 4608    // per-bucket slab capacity; mean 4096 -> +8 sigma
#define CHUNK    4096    // edges per partition block

typedef __attribute__((ext_vector_type(8))) short short8;
typedef __attribute__((ext_vector_type(4))) float f32x4;

__device__ inline unsigned packbf2(float f0, float f1) {   // RNE bf16 pair
    unsigned u0 = __float_as_uint(f0), u1 = __float_as_uint(f1);
    u0 = (u0 + 0x7fffu + ((u0 >> 16) & 1u)) >> 16;
    u1 = (u1 + 0x7fffu + ((u1 >> 16) & 1u)) >> 16;
    return u0 | (u1 << 16);
}

#define BFLO(p) __uint_as_float((p) << 16)
#define BFHI(p) __uint_as_float((p) & 0xffff0000u)

// prep: convert w1,w2 (8192 float2 pairs each) to bf16-packed uints + cursors.
__global__ void prep_k(const float* __restrict__ w1, const float* __restrict__ w2,
                       unsigned* __restrict__ wbf1, unsigned* __restrict__ wbf2,
                       int* __restrict__ gcur1, int* __restrict__ gcur2) {
    int b = blockIdx.x, t = threadIdx.x;
    if (b == 32) {
        if (t < C_BKT) { gcur1[t] = t * SLAB_CAP; gcur2[t] = t * SLAB_CAP; }
        return;
    }
    int p = b * 256 + t;                 // pair index 0..8191
    const float2 v1 = ((const float2*)w1)[p];
    const float2 v2 = ((const float2*)w2)[p];
    wbf1[p] = packbf2(v1.x, v1.y);
    wbf2[p] = packbf2(v2.x, v2.y);
}

// ---------------- fused partition || gemm1 ----------------
__device__ void partition_body(char* smem, int bx,
        const int* __restrict__ src1, const int* __restrict__ dst1,
        const int* __restrict__ src2, const int* __restrict__ dst2,
        unsigned* __restrict__ slab1, unsigned* __restrict__ slab2,
        int* __restrict__ gcur1, int* __restrict__ gcur2, int E, int NB) {
    unsigned* sorted = (unsigned*)smem;              // 16 KB
    unsigned* gpos   = sorted + CHUNK;               // 16 KB
    int* hist = (int*)(gpos + CHUNK);                // 1 KB
    int* loff = hist + 256;
    int* goff = loff + 256;
    int* cur  = goff + 256;

    int t = threadIdx.x;
    int dir = (bx >= NB) ? 1 : 0;
    int cb = dir ? (bx - NB) : bx;
    const int* srcp = dir ? src2 : src1;
    const int* dstp = dir ? dst2 : dst1;
    unsigned* slab = dir ? slab2 : slab1;
    int* gcur = dir ? gcur2 : gcur1;

    hist[t] = 0;
    __syncthreads();

    unsigned vv[16]; int bb[16];
    int base = cb * CHUNK;
    #pragma unroll
    for (int k = 0; k < 16; ++k) {
        int i = base + k * 256 + t;
        if (i < E) {
            int s = srcp[i], d = dstp[i];
            bb[k] = d >> 8;
            vv[k] = ((unsigned)(d & 255) << 16) | (unsigned)s;
            atomicAdd(&hist[bb[k]], 1);
        } else bb[k] = -1;
    }
    __syncthreads();

    int c = hist[t];
    if (t < C_BKT && c > 0) goff[t] = atomicAdd(&gcur[t], c);
    for (int d = 1; d < 256; d <<= 1) {
        int v = (t >= d) ? hist[t - d] : 0;
        __syncthreads();
        hist[t] += v;
        __syncthreads();
    }
    loff[t] = hist[t] - c;
    cur[t] = 0;
    __syncthreads();
    int nv = hist[255];

    #pragma unroll
    for (int k = 0; k < 16; ++k) {
        if (bb[k] >= 0) {
            int b = bb[k];
            int r = atomicAdd(&cur[b], 1);
            int p = loff[b] + r;
            sorted[p] = vv[k];
            int gp = goff[b] + r;
            gpos[p] = (gp < (b + 1) * SLAB_CAP) ? (unsigned)gp : 0xFFFFFFFFu;
        }
    }
    __syncthreads();

    for (int j = t; j < nv; j += 256) {
        unsigned gp = gpos[j];
        if (gp != 0xFFFFFFFFu) slab[gp] = sorted[j];
    }
}

// MFMA 16x16x32 bf16. Block = 4 waves; wave w -> rows [bx*64 + w*16, +16).
// A/B share the same per-lane k-mapping (k-permutation invariant).
// C/D: col=lane&15, row=(lane>>4)*4+reg  [m89-verified].
__device__ void gemm1_body(char* smem, int bx,
        const float* __restrict__ A, const unsigned* __restrict__ wbf,
        unsigned* __restrict__ zb, int M) {
    float* cst = (float*)smem;                       // 64*129*4 = 33 KB
    int t = threadIdx.x;
    int lane = t & 63, wv = t >> 6;
    int l16 = lane & 15, kg = lane >> 4;
    int rowBase = bx * 64 + wv * 16;
    int ar = rowBase + l16; if (ar >= M) ar = M - 1;

    f32x4 acc[8];
    #pragma unroll
    for (int ct = 0; ct < 8; ++ct) acc[ct] = (f32x4){0.f, 0.f, 0.f, 0.f};

    const float4* arow = (const float4*)(A + (size_t)ar * 128);
    #pragma unroll
    for (int kt = 0; kt < 4; ++kt) {
        float4 v0 = arow[kt * 8 + kg * 2];
        float4 v1 = arow[kt * 8 + kg * 2 + 1];
        uint4 au = make_uint4(packbf2(v0.x, v0.y), packbf2(v0.z, v0.w),
                              packbf2(v1.x, v1.y), packbf2(v1.z, v1.w));
        short8 a = *(short8*)&au;
        #pragma unroll
        for (int ct = 0; ct < 8; ++ct) {
            uint4 bu = *(const uint4*)(wbf + (size_t)(ct * 16 + l16) * 64 + kt * 16 + kg * 4);
            short8 b = *(short8*)&bu;
            acc[ct] = __builtin_amdgcn_mfma_f32_16x16x32_bf16(a, b, acc[ct], 0, 0, 0);
        }
    }

    #pragma unroll
    for (int ct = 0; ct < 8; ++ct)
        #pragma unroll
        for (int r = 0; r < 4; ++r)
            cst[(wv * 16 + kg * 4 + r) * 129 + ct * 16 + l16] = acc[ct][r];
    __syncthreads();

    int row = t & 63, q = t >> 6;
    int grow = bx * 64 + row;
    if (grow < M) {
        const float* src = cst + row * 129 + q * 32;
        unsigned pk[16];
        #pragma unroll
        for (int i = 0; i < 16; ++i) pk[i] = packbf2(src[2 * i], src[2 * i + 1]);
        uint4* dst = (uint4*)(zb + (size_t)grow * 64 + q * 16);
        #pragma unroll
        for (int qq = 0; qq < 4; ++qq)
            dst[qq] = make_uint4(pk[4 * qq], pk[4 * qq + 1], pk[4 * qq + 2], pk[4 * qq + 3]);
    }
}

__global__ __launch_bounds__(256) void pg_k(
        const int* __restrict__ src1, const int* __restrict__ dst1,
        const int* __restrict__ src2, const int* __restrict__ dst2,
        unsigned* __restrict__ slab1, unsigned* __restrict__ slab2,
        int* __restrict__ gcur1, int* __restrict__ gcur2, int E, int NB,
        const float* __restrict__ x, const unsigned* __restrict__ wbf1,
        unsigned* __restrict__ zb, int M) {
    __shared__ __align__(16) char smem[36864];
    int bx = blockIdx.x;
    if (bx < 2 * NB)
        partition_body(smem, bx, src1, dst1, src2, dst2,
                       slab1, slab2, gcur1, gcur2, E, NB);
    else
        gemm1_body(smem, bx - 2 * NB, x, wbf1, zb, M);
}

// Phase B: per (bucket, dir): counting-sort slab by node in LDS, emit exact CSR.
__global__ __launch_bounds__(256) void csr_k(
        const unsigned* __restrict__ slab1, const unsigned* __restrict__ slab2,
        const int* __restrict__ gcur1, const int* __restrict__ gcur2,
        unsigned short* __restrict__ list1, unsigned short* __restrict__ list2,
        unsigned* __restrict__ goff1, unsigned* __restrict__ goff2,
        unsigned short* __restrict__ gcnt1, unsigned short* __restrict__ gcnt2,
        int N) {
    __shared__ unsigned short srt[SLAB_CAP];
    __shared__ int cnt[256], loff[256], cur[256];

    int t = threadIdx.x;
    int dir = (blockIdx.x >= C_BKT) ? 1 : 0;
    int b = dir ? (blockIdx.x - C_BKT) : blockIdx.x;
    const unsigned* sl = (dir ? slab2 : slab1) + (size_t)b * SLAB_CAP;
    unsigned short* lst = dir ? list2 : list1;
    unsigned* goffN = dir ? goff2 : goff1;
    unsigned short* gcntN = dir ? gcnt2 : gcnt1;
    int nv = (dir ? gcur2 : gcur1)[b] - b * SLAB_CAP;
    if (nv > SLAB_CAP) nv = SLAB_CAP;

    cnt[t] = 0;
    __syncthreads();
    for (int j = t; j < nv; j += 256) atomicAdd(&cnt[sl[j] >> 16], 1);
    __syncthreads();

    int c = cnt[t];
    for (int d = 1; d < 256; d <<= 1) {
        int v = (t >= d) ? cnt[t - d] : 0;
        __syncthreads();
        cnt[t] += v;
        __syncthreads();
    }
    loff[t] = cnt[t] - c;
    cur[t] = 0;
    int node = b * 256 + t;
    if (node < N) {
        goffN[node] = (unsigned)(b * SLAB_CAP + loff[t]);
        gcntN[node] = (unsigned short)c;
    }
    __syncthreads();

    for (int j = t; j < nv; j += 256) {
        unsigned v = sl[j];
        int n = v >> 16;
        int r = atomicAdd(&cur[n], 1);
        srt[loff[n] + r] = (unsigned short)(v & 0xffffu);
    }
    __syncthreads();
    for (int j = t; j < nv; j += 256)
        lst[(size_t)b * SLAB_CAP + j] = srt[j];
}

// ---------------- fused gather + GEMM2 (16-wave blocks) ----------------
template<int B>
__device__ inline void batchsum(const unsigned short* __restrict__ lst, int o,
                                const unsigned* __restrict__ zb, int lane,
                                float& ax, float& ay) {
    unsigned idx[B], pv[B];
    #pragma unroll
    for (int u = 0; u < B; ++u) idx[u] = lst[o + u];
    #pragma unroll
    for (int u = 0; u < B; ++u) pv[u] = zb[(size_t)idx[u] * 64 + lane];
    float sx = 0.f, sy = 0.f;
    #pragma unroll
    for (int u = 0; u < B; ++u) { sx += BFLO(pv[u]); sy += BFHI(pv[u]); }
    ax += sx; ay += sy;
}

// Block = 64 nodes, 1024 threads = 16 waves. Gather phase: wave w handles
// nodes [w*4, w*4+4) (r9 per-node body; wave pool = 782*16 = 12.5K, matching
// r9's measured-55us parallelism). __syncthreads. MFMA phase: waves 0-3
// compute the 4 16-row tiles x wbf2 -> relu(+b2) f32.
__global__ __launch_bounds__(1024) void gg_k(
        const unsigned* __restrict__ zb,
        const unsigned* __restrict__ goff1, const unsigned short* __restrict__ gcnt1,
        const unsigned short* __restrict__ list1,
        const unsigned* __restrict__ goff2, const unsigned short* __restrict__ gcnt2,
        const unsigned short* __restrict__ list2,
        const float* __restrict__ b1, const unsigned* __restrict__ wbf,
        const float* __restrict__ bias2, float* __restrict__ O, int N) {
    __shared__ unsigned st[64][65];
    int t = threadIdx.x;
    int w = t >> 6, lane = t & 63;
    int rowBase = blockIdx.x * 64;
    float2 bb = ((const float2*)b1)[lane];

    // ---- phase 1: each wave gathers 4 nodes ----
    #pragma unroll
    for (int i = 0; i < 4; ++i) {
        int r = w * 4 + i;
        int g = __builtin_amdgcn_readfirstlane(rowBase + r);
        unsigned pk = 0;
        if (g < N) {
            float a1x = 0.f, a1y = 0.f, a2x = 0.f, a2y = 0.f;
            {
                int o = (int)goff1[g], c = (int)gcnt1[g], j = 0;
                for (; j + 16 <= c; j += 16) batchsum<16>(list1, o + j, zb, lane, a1x, a1y);
                if (j + 8 <= c) { batchsum<8>(list1, o + j, zb, lane, a1x, a1y); j += 8; }
                if (j + 4 <= c) { batchsum<4>(list1, o + j, zb, lane, a1x, a1y); j += 4; }
                for (; j < c; ++j) {
                    unsigned p = zb[(size_t)list1[o + j] * 64 + lane];
                    a1x += BFLO(p); a1y += BFHI(p);
                }
            }
            {
                int o = (int)goff2[g], c = (int)gcnt2[g], j = 0;
                for (; j + 16 <= c; j += 16) batchsum<16>(list2, o + j, zb, lane, a2x, a2y);
                if (j + 8 <= c) { batchsum<8>(list2, o + j, zb, lane, a2x, a2y); j += 8; }
                if (j + 4 <= c) { batchsum<4>(list2, o + j, zb, lane, a2x, a2y); j += 4; }
                for (; j < c; ++j) {
                    unsigned p = zb[(size_t)list2[o + j] * 64 + lane];
                    a2x += BFLO(p); a2y += BFHI(p);
                }
            }
            unsigned pz = zb[(size_t)g * 64 + lane];
            float bx = BFLO(pz) + bb.x, by = BFHI(pz) + bb.y;
            float ox = 0.5f * (fmaxf(bx + a1x, 0.f) + fmaxf(bx + a2x, 0.f));
            float oy = 0.5f * (fmaxf(by + a1y, 0.f) + fmaxf(by + a2y, 0.f));
            pk = packbf2(ox, oy);
        }
        st[r][lane] = pk;
    }

    __syncthreads();   // cross-wave: MFMA waves consume all 64 gathered rows
    if (w >= 4) return;

    // ---- phase 2: waves 0-3 MFMA rows [w*16, w*16+16) x wbf2 ----
    int l16 = lane & 15, kg = lane >> 4;
    uint4 a[4];
    #pragma unroll
    for (int kt = 0; kt < 4; ++kt)
        a[kt] = *(const uint4*)&st[w * 16 + l16][kt * 16 + kg * 4];

    #pragma unroll
    for (int ct = 0; ct < 8; ++ct) {
        f32x4 acc = (f32x4){0.f, 0.f, 0.f, 0.f};
        #pragma unroll
        for (int kt = 0; kt < 4; ++kt) {
            uint4 bu = *(const uint4*)(wbf + (size_t)(ct * 16 + l16) * 64 + kt * 16 + kg * 4);
            acc = __builtin_amdgcn_mfma_f32_16x16x32_bf16(
                *(short8*)&a[kt], *(short8*)&bu, acc, 0, 0, 0);
        }
        int col = ct * 16 + l16;
        float bv = bias2[col];
        #pragma unroll
        for (int r = 0; r < 4; ++r) {
            int grow = rowBase + w * 16 + kg * 4 + r;
            if (grow < N)
                O[(size_t)grow * 128 + col] = fmaxf(acc[r] + bv, 0.f);
        }
    }
}

extern "C" void kernel_launch(void* const* d_in, const int* in_sizes, int n_in,
                              void* d_out, int out_size, void* d_ws, size_t ws_size,
                              hipStream_t stream) {
    const float* x   = (const float*)d_in[0];
    const int*   ei  = (const int*)d_in[1];
    const int*   rei = (const int*)d_in[2];
    const float* w1  = (const float*)d_in[3];
    const float* b1  = (const float*)d_in[4];
    const float* w2  = (const float*)d_in[5];
    const float* b2  = (const float*)d_in[6];
    float* out = (float*)d_out;

    const int N = in_sizes[0] / 128;      // 50000
    const int E = in_sizes[1] / 2;        // 800000
    const size_t ND = (size_t)N * 128;
    const size_t SL = (size_t)C_BKT * SLAB_CAP;   // 903168

    // ws layout (~25 MB)
    unsigned* zb    = (unsigned*)d_ws;            // N*64  (bf16 z, 12.8 MB)
    unsigned* wbf1  = zb + ND / 2;                // 8192  (bf16 w1, 32 KB)
    unsigned* wbf2  = wbf1 + 8192;                // 8192
    unsigned* slab1 = wbf2 + 8192;                // SL
    unsigned* slab2 = slab1 + SL;                 // SL
    unsigned* goff1 = slab2 + SL;                 // N
    unsigned* goff2 = goff1 + N;                  // N
    int*      gcur1 = (int*)(goff2 + N);          // C_BKT
    int*      gcur2 = gcur1 + C_BKT;              // C_BKT
    unsigned short* gcnt1 = (unsigned short*)(gcur2 + C_BKT);  // N
    unsigned short* gcnt2 = gcnt1 + N;            // N
    unsigned short* list1 = gcnt2 + N;            // SL
    unsigned short* list2 = list1 + SL;           // SL

    const int* src1 = ei,  *dst1 = ei + E;
    const int* src2 = rei, *dst2 = rei + E;

    // 1. weight bf16 convert (8192 pairs = 32 blocks) + slab cursor init
    prep_k<<<33, 256, 0, stream>>>(w1, w2, wbf1, wbf2, gcur1, gcur2);

    // 2. fused: partition (392 blocks) || gemm1 (782 blocks)
    int NB = (E + CHUNK - 1) / CHUNK;   // 196
    int gB = (N + 63) / 64;             // 782
    pg_k<<<2 * NB + gB, 256, 0, stream>>>(src1, dst1, src2, dst2,
                                          slab1, slab2, gcur1, gcur2, E, NB,
                                          x, wbf1, zb, N);

    // 3. in-LDS counting sort -> exact CSR
    csr_k<<<2 * C_BKT, 256, 0, stream>>>(slab1, slab2, gcur1, gcur2,
                                         list1, list2, goff1, goff2,
                                         gcnt1, gcnt2, N);

    // 4. fused gather + activation + GEMM2 -> out (f32); 16-wave blocks
    gg_k<<<gB, 1024, 0, stream>>>(zb, goff1, gcnt1, list1,
                                  goff2, gcnt2, list2, b1, wbf2, b2, out, N);
}

// Round 17
// 124.250 us; speedup vs baseline: 1.2343x; 1.0485x over previous
//
#include <hip/hip_runtime.h>
#include <hip/hip_bf16.h>

// ---------------------------------------------------------------------------
// BidirectionalGINConv: out = relu(0.5*(gin(ei) + gin(rei)))
// FINAL (= r13, the measured-best configuration, 124us):
//   z = x@w1^T                 (bf16 MFMA GEMM, fused into partition launch)
//   adjacency: partition into 256-node bucket slabs -> in-LDS counting sort CSR
//   agg_i = segsum(z[src_i])   (1-node-per-wave gather, 16/8/4 batches)
//   s = 0.5*(relu(z+b1+agg1)+relu(z+b1+agg2))  (fused in gather, bf16 out)
//   out = relu(s@w2^T + b2)    (bf16 MFMA GEMM, f32 epilogue)
// LESSONS (counter-verified):
//   r1:  f32 global atomics: each = full RMW transaction (1.6GB WRITE_SIZE).
//   r3:  scattered 4B stores: no write-allocate -> 64B/store (95MB for 6.4MB).
//   r7:  LDS f32 atomicAdd = CAS retry loop -> never on critical path.
//   r10: blockIdx%8->XCD affinity is not a contract; 4x less MLP regressed.
//   r11: >16-deep software batches get serialized by the register allocator.
//   r12: partition||gemm1 single-dispatch fusion saved ~17us.
//   r13: gather plateau 55us @ 2.75TB/s LLC service, reproduced 3x. Floor
//        ~40us (109MB compulsory 8-XCD z replication); gap = L2 capacity
//        misses (12.8MB z vs 4MB L2, random). fp8 z fails error budget.
//   r14/r15: gather+gemm2 fusion (256thr: Occ 29%; 1024thr: barrier skew,
//        Occ 51%) both lose to split. Gather must be its own kernel.
//   r16: compile error from a mangled epilogue line during revert; fixed.
// ---------------------------------------------------------------------------

#define C_BKT    196     // coarse buckets: b = dst>>8 (256 nodes each)
#define SLAB_CAP 4608    // per-bucket slab capacity; mean 4096 -> +8 sigma
#define CHUNK    4096    // edges per partition block

typedef __attribute__((ext_vector_type(8))) short short8;
typedef __attribute__((ext_vector_type(4))) float f32x4;

__device__ inline unsigned packbf2(float f0, float f1) {   // RNE bf16 pair
    unsigned u0 = __float_as_uint(f0), u1 = __float_as_uint(f1);
    u0 = (u0 + 0x7fffu + ((u0 >> 16) & 1u)) >> 16;
    u1 = (u1 + 0x7fffu + ((u1 >> 16) & 1u)) >> 16;
    return u0 | (u1 << 16);
}

#define BFLO(p) __uint_as_float((p) << 16)
#define BFHI(p) __uint_as_float((p) & 0xffff0000u)

// prep: convert w1,w2 (8192 float2 pairs each) to bf16-packed uints + cursors.
__global__ void prep_k(const float* __restrict__ w1, const float* __restrict__ w2,
                       unsigned* __restrict__ wbf1, unsigned* __restrict__ wbf2,
                       int* __restrict__ gcur1, int* __restrict__ gcur2) {
    int b = blockIdx.x, t = threadIdx.x;
    if (b == 32) {
        if (t < C_BKT) { gcur1[t] = t * SLAB_CAP; gcur2[t] = t * SLAB_CAP; }
        return;
    }
    int p = b * 256 + t;                 // pair index 0..8191
    const float2 v1 = ((const float2*)w1)[p];
    const float2 v2 = ((const float2*)w2)[p];
    wbf1[p] = packbf2(v1.x, v1.y);
    wbf2[p] = packbf2(v2.x, v2.y);
}

// ---------------- fused partition || gemm1 ----------------
__device__ void partition_body(char* smem, int bx,
        const int* __restrict__ src1, const int* __restrict__ dst1,
        const int* __restrict__ src2, const int* __restrict__ dst2,
        unsigned* __restrict__ slab1, unsigned* __restrict__ slab2,
        int* __restrict__ gcur1, int* __restrict__ gcur2, int E, int NB) {
    unsigned* sorted = (unsigned*)smem;              // 16 KB
    unsigned* gpos   = sorted + CHUNK;               // 16 KB
    int* hist = (int*)(gpos + CHUNK);                // 1 KB
    int* loff = hist + 256;
    int* goff = loff + 256;
    int* cur  = goff + 256;

    int t = threadIdx.x;
    int dir = (bx >= NB) ? 1 : 0;
    int cb = dir ? (bx - NB) : bx;
    const int* srcp = dir ? src2 : src1;
    const int* dstp = dir ? dst2 : dst1;
    unsigned* slab = dir ? slab2 : slab1;
    int* gcur = dir ? gcur2 : gcur1;

    hist[t] = 0;
    __syncthreads();

    unsigned vv[16]; int bb[16];
    int base = cb * CHUNK;
    #pragma unroll
    for (int k = 0; k < 16; ++k) {
        int i = base + k * 256 + t;
        if (i < E) {
            int s = srcp[i], d = dstp[i];
            bb[k] = d >> 8;
            vv[k] = ((unsigned)(d & 255) << 16) | (unsigned)s;
            atomicAdd(&hist[bb[k]], 1);
        } else bb[k] = -1;
    }
    __syncthreads();

    int c = hist[t];
    if (t < C_BKT && c > 0) goff[t] = atomicAdd(&gcur[t], c);
    for (int d = 1; d < 256; d <<= 1) {
        int v = (t >= d) ? hist[t - d] : 0;
        __syncthreads();
        hist[t] += v;
        __syncthreads();
    }
    loff[t] = hist[t] - c;
    cur[t] = 0;
    __syncthreads();
    int nv = hist[255];

    #pragma unroll
    for (int k = 0; k < 16; ++k) {
        if (bb[k] >= 0) {
            int b = bb[k];
            int r = atomicAdd(&cur[b], 1);
            int p = loff[b] + r;
            sorted[p] = vv[k];
            int gp = goff[b] + r;
            gpos[p] = (gp < (b + 1) * SLAB_CAP) ? (unsigned)gp : 0xFFFFFFFFu;
        }
    }
    __syncthreads();

    for (int j = t; j < nv; j += 256) {
        unsigned gp = gpos[j];
        if (gp != 0xFFFFFFFFu) slab[gp] = sorted[j];
    }
}

// MFMA 16x16x32 bf16. Block = 4 waves; wave w -> rows [bx*64 + w*16, +16).
// A/B share the same per-lane k-mapping (k-permutation invariant).
// C/D: col=lane&15, row=(lane>>4)*4+reg  [m89-verified].
__device__ void gemm1_body(char* smem, int bx,
        const float* __restrict__ A, const unsigned* __restrict__ wbf,
        unsigned* __restrict__ zb, int M) {
    float* cst = (float*)smem;                       // 64*129*4 = 33 KB
    int t = threadIdx.x;
    int lane = t & 63, wv = t >> 6;
    int l16 = lane & 15, kg = lane >> 4;
    int rowBase = bx * 64 + wv * 16;
    int ar = rowBase + l16; if (ar >= M) ar = M - 1;

    f32x4 acc[8];
    #pragma unroll
    for (int ct = 0; ct < 8; ++ct) acc[ct] = (f32x4){0.f, 0.f, 0.f, 0.f};

    const float4* arow = (const float4*)(A + (size_t)ar * 128);
    #pragma unroll
    for (int kt = 0; kt < 4; ++kt) {
        float4 v0 = arow[kt * 8 + kg * 2];
        float4 v1 = arow[kt * 8 + kg * 2 + 1];
        uint4 au = make_uint4(packbf2(v0.x, v0.y), packbf2(v0.z, v0.w),
                              packbf2(v1.x, v1.y), packbf2(v1.z, v1.w));
        short8 a = *(short8*)&au;
        #pragma unroll
        for (int ct = 0; ct < 8; ++ct) {
            uint4 bu = *(const uint4*)(wbf + (size_t)(ct * 16 + l16) * 64 + kt * 16 + kg * 4);
            short8 b = *(short8*)&bu;
            acc[ct] = __builtin_amdgcn_mfma_f32_16x16x32_bf16(a, b, acc[ct], 0, 0, 0);
        }
    }

    #pragma unroll
    for (int ct = 0; ct < 8; ++ct)
        #pragma unroll
        for (int r = 0; r < 4; ++r)
            cst[(wv * 16 + kg * 4 + r) * 129 + ct * 16 + l16] = acc[ct][r];
    __syncthreads();

    int row = t & 63, q = t >> 6;
    int grow = bx * 64 + row;
    if (grow < M) {
        const float* src = cst + row * 129 + q * 32;
        unsigned pk[16];
        #pragma unroll
        for (int i = 0; i < 16; ++i) pk[i] = packbf2(src[2 * i], src[2 * i + 1]);
        uint4* dst = (uint4*)(zb + (size_t)grow * 64 + q * 16);
        #pragma unroll
        for (int qq = 0; qq < 4; ++qq)
            dst[qq] = make_uint4(pk[4 * qq], pk[4 * qq + 1], pk[4 * qq + 2], pk[4 * qq + 3]);
    }
}

__global__ __launch_bounds__(256) void pg_k(
        const int* __restrict__ src1, const int* __restrict__ dst1,
        const int* __restrict__ src2, const int* __restrict__ dst2,
        unsigned* __restrict__ slab1, unsigned* __restrict__ slab2,
        int* __restrict__ gcur1, int* __restrict__ gcur2, int E, int NB,
        const float* __restrict__ x, const unsigned* __restrict__ wbf1,
        unsigned* __restrict__ zb, int M) {
    __shared__ __align__(16) char smem[36864];
    int bx = blockIdx.x;
    if (bx < 2 * NB)
        partition_body(smem, bx, src1, dst1, src2, dst2,
                       slab1, slab2, gcur1, gcur2, E, NB);
    else
        gemm1_body(smem, bx - 2 * NB, x, wbf1, zb, M);
}

// Phase B: per (bucket, dir): counting-sort slab by node in LDS, emit exact CSR.
__global__ __launch_bounds__(256) void csr_k(
        const unsigned* __restrict__ slab1, const unsigned* __restrict__ slab2,
        const int* __restrict__ gcur1, const int* __restrict__ gcur2,
        unsigned short* __restrict__ list1, unsigned short* __restrict__ list2,
        unsigned* __restrict__ goff1, unsigned* __restrict__ goff2,
        unsigned short* __restrict__ gcnt1, unsigned short* __restrict__ gcnt2,
        int N) {
    __shared__ unsigned short srt[SLAB_CAP];
    __shared__ int cnt[256], loff[256], cur[256];

    int t = threadIdx.x;
    int dir = (blockIdx.x >= C_BKT) ? 1 : 0;
    int b = dir ? (blockIdx.x - C_BKT) : blockIdx.x;
    const unsigned* sl = (dir ? slab2 : slab1) + (size_t)b * SLAB_CAP;
    unsigned short* lst = dir ? list2 : list1;
    unsigned* goffN = dir ? goff2 : goff1;
    unsigned short* gcntN = dir ? gcnt2 : gcnt1;
    int nv = (dir ? gcur2 : gcur1)[b] - b * SLAB_CAP;
    if (nv > SLAB_CAP) nv = SLAB_CAP;

    cnt[t] = 0;
    __syncthreads();
    for (int j = t; j < nv; j += 256) atomicAdd(&cnt[sl[j] >> 16], 1);
    __syncthreads();

    int c = cnt[t];
    for (int d = 1; d < 256; d <<= 1) {
        int v = (t >= d) ? cnt[t - d] : 0;
        __syncthreads();
        cnt[t] += v;
        __syncthreads();
    }
    loff[t] = cnt[t] - c;
    cur[t] = 0;
    int node = b * 256 + t;
    if (node < N) {
        goffN[node] = (unsigned)(b * SLAB_CAP + loff[t]);
        gcntN[node] = (unsigned short)c;
    }
    __syncthreads();

    for (int j = t; j < nv; j += 256) {
        unsigned v = sl[j];
        int n = v >> 16;
        int r = atomicAdd(&cur[n], 1);
        srt[loff[n] + r] = (unsigned short)(v & 0xffffu);
    }
    __syncthreads();
    for (int j = t; j < nv; j += 256)
        lst[(size_t)b * SLAB_CAP + j] = srt[j];
}

// GEMM2: A = s (bf16), out = relu(A@W^T + b2) f32. Direct stores.
__global__ __launch_bounds__(256) void gemm2_mfma_k(
        const unsigned* __restrict__ sB, const unsigned* __restrict__ wbf,
        const float* __restrict__ bias, float* __restrict__ O, int M) {
    int t = threadIdx.x;
    int lane = t & 63, wv = t >> 6;
    int l16 = lane & 15, kg = lane >> 4;
    int rowBase = blockIdx.x * 64 + wv * 16;
    int ar = rowBase + l16; if (ar >= M) ar = M - 1;

    f32x4 acc[8];
    #pragma unroll
    for (int ct = 0; ct < 8; ++ct) acc[ct] = (f32x4){0.f, 0.f, 0.f, 0.f};

    #pragma unroll
    for (int kt = 0; kt < 4; ++kt) {
        uint4 au = *(const uint4*)(sB + (size_t)ar * 64 + kt * 16 + kg * 4);
        short8 a = *(short8*)&au;
        #pragma unroll
        for (int ct = 0; ct < 8; ++ct) {
            uint4 bu = *(const uint4*)(wbf + (size_t)(ct * 16 + l16) * 64 + kt * 16 + kg * 4);
            short8 b = *(short8*)&bu;
            acc[ct] = __builtin_amdgcn_mfma_f32_16x16x32_bf16(a, b, acc[ct], 0, 0, 0);
        }
    }

    #pragma unroll
    for (int ct = 0; ct < 8; ++ct) {
        int col = ct * 16 + l16;
        float bv = bias[col];
        #pragma unroll
        for (int r = 0; r < 4; ++r) {
            int grow = rowBase + kg * 4 + r;
            if (grow < M)
                O[(size_t)grow * 128 + col] = fmaxf(acc[ct][r] + bv, 0.f);
        }
    }
}

// ---------------- gather (r9 structure: measured 55us, 3x reproduced) ------
template<int B>
__device__ inline void batchsum(const unsigned short* __restrict__ lst, int o,
                                const unsigned* __restrict__ zb, int lane,
                                float& ax, float& ay) {
    unsigned idx[B], pv[B];
    #pragma unroll
    for (int u = 0; u < B; ++u) idx[u] = lst[o + u];
    #pragma unroll
    for (int u = 0; u < B; ++u) pv[u] = zb[(size_t)idx[u] * 64 + lane];
    float sx = 0.f, sy = 0.f;
    #pragma unroll
    for (int u = 0; u < B; ++u) { sx += BFLO(pv[u]); sy += BFHI(pv[u]); }
    ax += sx; ay += sy;
}

// One node per 64-lane wave; bf16 z rows (uint = 2 elems/lane).
// 16/8/4-deep pipelined loads; f32 accumulate; bf16-packed s output.
__global__ __launch_bounds__(256) void gather_fuse_k(
        const unsigned* __restrict__ zb,
        const unsigned* __restrict__ goff1, const unsigned short* __restrict__ gcnt1,
        const unsigned short* __restrict__ list1,
        const unsigned* __restrict__ goff2, const unsigned short* __restrict__ gcnt2,
        const unsigned short* __restrict__ list2,
        const float* __restrict__ b1, unsigned* __restrict__ sOut, int N) {
    int g = __builtin_amdgcn_readfirstlane(blockIdx.x * 4 + (threadIdx.x >> 6));
    if (g >= N) return;
    int lane = threadIdx.x & 63;

    float a1x = 0.f, a1y = 0.f, a2x = 0.f, a2y = 0.f;

    {
        int o = (int)goff1[g], c = (int)gcnt1[g], i = 0;
        for (; i + 16 <= c; i += 16) batchsum<16>(list1, o + i, zb, lane, a1x, a1y);
        if (i + 8 <= c) { batchsum<8>(list1, o + i, zb, lane, a1x, a1y); i += 8; }
        if (i + 4 <= c) { batchsum<4>(list1, o + i, zb, lane, a1x, a1y); i += 4; }
        for (; i < c; ++i) {
            unsigned p = zb[(size_t)list1[o + i] * 64 + lane];
            a1x += BFLO(p); a1y += BFHI(p);
        }
    }
    {
        int o = (int)goff2[g], c = (int)gcnt2[g], i = 0;
        for (; i + 16 <= c; i += 16) batchsum<16>(list2, o + i, zb, lane, a2x, a2y);
        if (i + 8 <= c) { batchsum<8>(list2, o + i, zb, lane, a2x, a2y); i += 8; }
        if (i + 4 <= c) { batchsum<4>(list2, o + i, zb, lane, a2x, a2y); i += 4; }
        for (; i < c; ++i) {
            unsigned p = zb[(size_t)list2[o + i] * 64 + lane];
            a2x += BFLO(p); a2y += BFHI(p);
        }
    }

    unsigned pz = zb[(size_t)g * 64 + lane];
    float2 bb = ((const float2*)b1)[lane];
    float bx = BFLO(pz) + bb.x, by = BFHI(pz) + bb.y;
    float ox = 0.5f * (fmaxf(bx + a1x, 0.f) + fmaxf(bx + a2x, 0.f));
    float oy = 0.5f * (fmaxf(by + a1y, 0.f) + fmaxf(by + a2y, 0.f));
    sOut[(size_t)g * 64 + lane] = packbf2(ox, oy);
}

extern "C" void kernel_launch(void* const* d_in, const int* in_sizes, int n_in,
                              void* d_out, int out_size, void* d_ws, size_t ws_size,
                              hipStream_t stream) {
    const float* x   = (const float*)d_in[0];
    const int*   ei  = (const int*)d_in[1];
    const int*   rei = (const int*)d_in[2];
    const float* w1  = (const float*)d_in[3];
    const float* b1  = (const float*)d_in[4];
    const float* w2  = (const float*)d_in[5];
    const float* b2  = (const float*)d_in[6];
    float* out = (float*)d_out;

    const int N = in_sizes[0] / 128;      // 50000
    const int E = in_sizes[1] / 2;        // 800000
    const size_t ND = (size_t)N * 128;
    const size_t SL = (size_t)C_BKT * SLAB_CAP;   // 903168

    // ws layout (~38 MB)
    unsigned* zb    = (unsigned*)d_ws;            // N*64  (bf16 z, 12.8 MB)
    unsigned* sb    = zb + ND / 2;                // N*64  (bf16 s, 12.8 MB)
    unsigned* wbf1  = sb + ND / 2;                // 8192  (bf16 w1, 32 KB)
    unsigned* wbf2  = wbf1 + 8192;                // 8192
    unsigned* slab1 = wbf2 + 8192;                // SL
    unsigned* slab2 = slab1 + SL;                 // SL
    unsigned* goff1 = slab2 + SL;                 // N
    unsigned* goff2 = goff1 + N;                  // N
    int*      gcur1 = (int*)(goff2 + N);          // C_BKT
    int*      gcur2 = gcur1 + C_BKT;              // C_BKT
    unsigned short* gcnt1 = (unsigned short*)(gcur2 + C_BKT);  // N
    unsigned short* gcnt2 = gcnt1 + N;            // N
    unsigned short* list1 = gcnt2 + N;            // SL
    unsigned short* list2 = list1 + SL;           // SL

    const int* src1 = ei,  *dst1 = ei + E;
    const int* src2 = rei, *dst2 = rei + E;

    // 1. weight bf16 convert (8192 pairs = 32 blocks) + slab cursor init
    prep_k<<<33, 256, 0, stream>>>(w1, w2, wbf1, wbf2, gcur1, gcur2);

    // 2. fused: partition (392 blocks) || gemm1 (782 blocks)
    int NB = (E + CHUNK - 1) / CHUNK;   // 196
    int gB = (N + 63) / 64;             // 782
    pg_k<<<2 * NB + gB, 256, 0, stream>>>(src1, dst1, src2, dst2,
                                          slab1, slab2, gcur1, gcur2, E, NB,
                                          x, wbf1, zb, N);

    // 3. in-LDS counting sort -> exact CSR
    csr_k<<<2 * C_BKT, 256, 0, stream>>>(slab1, slab2, gcur1, gcur2,
                                         list1, list2, goff1, goff2,
                                         gcnt1, gcnt2, N);

    // 4. fused gather + activation -> s (bf16); 1 node per wave
    gather_fuse_k<<<(N + 3) / 4, 256, 0, stream>>>(zb, goff1, gcnt1, list1,
                                                   goff2, gcnt2, list2, b1, sb, N);

    // 5. out = relu(s @ w2^T + b2)  (MFMA, f32 out)
    gemm2_mfma_k<<<gB, 256, 0, stream>>>(sb, wbf2, b2, out, N);
}